// Round 1
// baseline (1098.753 us; speedup 1.0000x reference)
//
#include <hip/hip_runtime.h>
#include <hip/hip_bf16.h>
#include <math.h>

// Problem constants (match reference)
#define NN 50000
#define EE 800000
#define INF_ 300
#define HIDF 256
#define GG 64

// ---------------------------------------------------------------------------
// CSR build: histogram of dst, exclusive scan, scatter src ids
// ---------------------------------------------------------------------------
__global__ void count_dst_k(const int* __restrict__ dst, int* __restrict__ cnt, int E) {
    int e = blockIdx.x * blockDim.x + threadIdx.x;
    if (e < E) atomicAdd(&cnt[dst[e]], 1);
}

__global__ void scan1_k(const int* __restrict__ cnt, int* __restrict__ tmp,
                        int* __restrict__ bsums, int n) {
    __shared__ int sd[256];
    int t = threadIdx.x;
    int i = blockIdx.x * 256 + t;
    sd[t] = (i < n) ? cnt[i] : 0;
    __syncthreads();
    #pragma unroll
    for (int off = 1; off < 256; off <<= 1) {
        int add = (t >= off) ? sd[t - off] : 0;
        __syncthreads();
        sd[t] += add;
        __syncthreads();
    }
    if (i < n) tmp[i] = sd[t];
    if (t == 255) bsums[blockIdx.x] = sd[255];
}

__global__ void scan2_k(int* __restrict__ bsums, int nb) {
    __shared__ int sd[256];
    int t = threadIdx.x;
    sd[t] = (t < nb) ? bsums[t] : 0;
    __syncthreads();
    #pragma unroll
    for (int off = 1; off < 256; off <<= 1) {
        int add = (t >= off) ? sd[t - off] : 0;
        __syncthreads();
        sd[t] += add;
        __syncthreads();
    }
    if (t < nb) bsums[t] = sd[t];
}

__global__ void scan3_k(const int* __restrict__ tmp, const int* __restrict__ cnt,
                        const int* __restrict__ bsums, int* __restrict__ row_off,
                        int* __restrict__ wr, int n) {
    int i = blockIdx.x * 256 + threadIdx.x;
    if (i >= n) return;
    int base = (blockIdx.x > 0) ? bsums[blockIdx.x - 1] : 0;
    int incl = tmp[i] + base;
    row_off[i + 1] = incl;
    wr[i] = incl - cnt[i];
    if (i == 0) row_off[0] = 0;
}

__global__ void scatter_k(const int* __restrict__ src, const int* __restrict__ dst,
                          int* __restrict__ wr, int* __restrict__ csr_src, int E) {
    int e = blockIdx.x * blockDim.x + threadIdx.x;
    if (e < E) {
        int d = dst[e];
        int pos = atomicAdd(&wr[d], 1);
        csr_src[pos] = src[e];
    }
}

// ---------------------------------------------------------------------------
// fp32 GEMM: C[M,256] = A[M,K] @ B[K,256].  64x64 tile, 256 thr, 4x4 micro.
// ---------------------------------------------------------------------------
__global__ __launch_bounds__(256) void gemm_f32(const float* __restrict__ A,
                                                const float* __restrict__ B,
                                                float* __restrict__ C, int M, int K) {
    __shared__ float sA[16][64];  // [k][m]
    __shared__ float sB[16][64];  // [k][n]
    const int tid = threadIdx.x;
    const int tr = tid >> 4, tc = tid & 15;
    const int r0 = tr * 4, c0 = tc * 4;
    const int bm = blockIdx.x * 64;
    const int bn = blockIdx.y * 64;

    float acc[4][4] = {};

    const int aRow = tid >> 2;           // 0..63
    const int aK   = (tid & 3) * 4;      // 0,4,8,12
    const int bRow = tid >> 4;           // 0..15
    const int bCol = (tid & 15) * 4;     // 0..60
    const bool aValid = (bm + aRow) < M;
    const float* Arow = A + (size_t)(bm + aRow) * K;
    const int nK = (K + 15) >> 4;

    for (int t = 0; t < nK; ++t) {
        int k0 = t * 16;
        // A tile (guarded)
        if (aValid && (k0 + aK + 3) < K) {
            float4 v = *(const float4*)(Arow + k0 + aK);
            sA[aK + 0][aRow] = v.x;
            sA[aK + 1][aRow] = v.y;
            sA[aK + 2][aRow] = v.z;
            sA[aK + 3][aRow] = v.w;
        } else {
            #pragma unroll
            for (int j = 0; j < 4; ++j) {
                int k = k0 + aK + j;
                sA[aK + j][aRow] = (aValid && k < K) ? Arow[k] : 0.f;
            }
        }
        // B tile
        {
            int k = k0 + bRow;
            float4 v = make_float4(0.f, 0.f, 0.f, 0.f);
            if (k < K) v = *(const float4*)(B + (size_t)k * 256 + bn + bCol);
            *(float4*)&sB[bRow][bCol] = v;
        }
        __syncthreads();
        #pragma unroll
        for (int k = 0; k < 16; ++k) {
            float4 a4 = *(float4*)&sA[k][r0];
            float4 b4 = *(float4*)&sB[k][c0];
            acc[0][0] += a4.x * b4.x; acc[0][1] += a4.x * b4.y; acc[0][2] += a4.x * b4.z; acc[0][3] += a4.x * b4.w;
            acc[1][0] += a4.y * b4.x; acc[1][1] += a4.y * b4.y; acc[1][2] += a4.y * b4.z; acc[1][3] += a4.y * b4.w;
            acc[2][0] += a4.z * b4.x; acc[2][1] += a4.z * b4.y; acc[2][2] += a4.z * b4.z; acc[2][3] += a4.z * b4.w;
            acc[3][0] += a4.w * b4.x; acc[3][1] += a4.w * b4.y; acc[3][2] += a4.w * b4.z; acc[3][3] += a4.w * b4.w;
        }
        __syncthreads();
    }
    #pragma unroll
    for (int i = 0; i < 4; ++i) {
        int m = bm + r0 + i;
        if (m < M) {
            float4 v = make_float4(acc[i][0], acc[i][1], acc[i][2], acc[i][3]);
            *(float4*)(C + (size_t)m * 256 + bn + c0) = v;
        }
    }
}

// ---------------------------------------------------------------------------
// Per-node attention scores: als[n,h] = <h[n,h,:], a_src[h,:]>, same for ald.
// One wave per node.
// ---------------------------------------------------------------------------
template <int NH>
__global__ __launch_bounds__(256) void calc_alpha_k(const float* __restrict__ hf,
                                                    const float* __restrict__ a_s,
                                                    const float* __restrict__ a_d,
                                                    float* __restrict__ als,
                                                    float* __restrict__ ald, int n) {
    int gw = (blockIdx.x * blockDim.x + threadIdx.x) >> 6;
    int lane = threadIdx.x & 63;
    if (gw >= n) return;
    const float* hr = hf + (size_t)gw * 256;
    float ps[4], pd[4];
    #pragma unroll
    for (int j = 0; j < 4; ++j) {
        float v = hr[j * 64 + lane];
        ps[j] = v * a_s[j * 64 + lane];
        pd[j] = v * a_d[j * 64 + lane];
    }
    if (NH == 1) {
        ps[0] = (ps[0] + ps[1]) + (ps[2] + ps[3]);
        pd[0] = (pd[0] + pd[1]) + (pd[2] + pd[3]);
    }
    #pragma unroll
    for (int h = 0; h < NH; ++h) {
        float s = ps[h], d = pd[h];
        #pragma unroll
        for (int off = 32; off > 0; off >>= 1) {
            s += __shfl_xor(s, off, 64);
            d += __shfl_xor(d, off, 64);
        }
        if (lane == 0) {
            als[gw * NH + h] = s;
            ald[gw * NH + h] = d;
        }
    }
}

// ---------------------------------------------------------------------------
// GAT aggregation: one wave per dst node. Segment softmax + weighted sum.
// ---------------------------------------------------------------------------
__device__ __forceinline__ float leaky02(float x) { return (x > 0.f) ? x : 0.2f * x; }

template <int NH>
__global__ __launch_bounds__(256) void gat_agg_k(const float* __restrict__ hf,
                                                 const float* __restrict__ als,
                                                 const float* __restrict__ ald,
                                                 const int* __restrict__ row_off,
                                                 const int* __restrict__ csr_src,
                                                 const float* __restrict__ bias,
                                                 float* __restrict__ out, int n,
                                                 int do_elu) {
    int gw = (blockIdx.x * blockDim.x + threadIdx.x) >> 6;
    int lane = threadIdx.x & 63;
    if (gw >= n) return;
    const int i = gw;
    const int e0 = row_off[i], e1 = row_off[i + 1];

    float adv[NH], aself[NH];
    if (NH == 4) {
        float4 v = *(const float4*)(ald + (size_t)i * 4);
        adv[0] = v.x; if (NH > 1) { adv[1] = v.y; adv[2] = v.z; adv[3] = v.w; }
        float4 u = *(const float4*)(als + (size_t)i * 4);
        aself[0] = u.x; if (NH > 1) { aself[1] = u.y; aself[2] = u.z; aself[3] = u.w; }
    } else {
        adv[0] = ald[i];
        aself[0] = als[i];
    }

    // pass 1: segment max (self-loop seeds the max on every lane)
    float m[NH];
    #pragma unroll
    for (int h = 0; h < NH; ++h) m[h] = leaky02(aself[h] + adv[h]);
    for (int e = e0 + lane; e < e1; e += 64) {
        int s = csr_src[e];
        if (NH == 4) {
            float4 v = *(const float4*)(als + (size_t)s * 4);
            m[0] = fmaxf(m[0], leaky02(v.x + adv[0]));
            m[1] = fmaxf(m[1], leaky02(v.y + adv[1]));
            m[2] = fmaxf(m[2], leaky02(v.z + adv[2]));
            m[3] = fmaxf(m[3], leaky02(v.w + adv[3]));
        } else {
            m[0] = fmaxf(m[0], leaky02(als[s] + adv[0]));
        }
    }
    #pragma unroll
    for (int h = 0; h < NH; ++h)
        #pragma unroll
        for (int off = 32; off > 0; off >>= 1)
            m[h] = fmaxf(m[h], __shfl_xor(m[h], off, 64));

    // pass 2: weights + weighted feature accumulation (lane owns 4 dims)
    float acc0 = 0.f, acc1 = 0.f, acc2 = 0.f, acc3 = 0.f;
    float denom[NH];
    #pragma unroll
    for (int h = 0; h < NH; ++h) denom[h] = 0.f;

    {   // self loop
        float w[NH];
        #pragma unroll
        for (int h = 0; h < NH; ++h) {
            w[h] = expf(leaky02(aself[h] + adv[h]) - m[h]);
            denom[h] += w[h];
        }
        const float* hr = hf + (size_t)i * 256;
        acc0 += w[0] * hr[lane];
        acc1 += w[NH == 4 ? 1 : 0] * hr[64 + lane];
        acc2 += w[NH == 4 ? 2 : 0] * hr[128 + lane];
        acc3 += w[NH == 4 ? 3 : 0] * hr[192 + lane];
    }
    for (int e = e0; e < e1; ++e) {
        int s = csr_src[e];
        float w[NH];
        if (NH == 4) {
            float4 v = *(const float4*)(als + (size_t)s * 4);
            w[0] = expf(leaky02(v.x + adv[0]) - m[0]);
            w[1] = expf(leaky02(v.y + adv[1]) - m[1]);
            w[2] = expf(leaky02(v.z + adv[2]) - m[2]);
            w[3] = expf(leaky02(v.w + adv[3]) - m[3]);
            denom[0] += w[0]; denom[1] += w[1]; denom[2] += w[2]; denom[3] += w[3];
        } else {
            w[0] = expf(leaky02(als[s] + adv[0]) - m[0]);
            denom[0] += w[0];
        }
        const float* hr = hf + (size_t)s * 256;
        acc0 += w[0] * hr[lane];
        acc1 += w[NH == 4 ? 1 : 0] * hr[64 + lane];
        acc2 += w[NH == 4 ? 2 : 0] * hr[128 + lane];
        acc3 += w[NH == 4 ? 3 : 0] * hr[192 + lane];
    }

    float o0 = acc0 / (denom[0] + 1e-16f) + bias[lane];
    float o1 = acc1 / (denom[NH == 4 ? 1 : 0] + 1e-16f) + bias[64 + lane];
    float o2 = acc2 / (denom[NH == 4 ? 2 : 0] + 1e-16f) + bias[128 + lane];
    float o3 = acc3 / (denom[NH == 4 ? 3 : 0] + 1e-16f) + bias[192 + lane];
    if (do_elu) {
        o0 = (o0 > 0.f) ? o0 : expf(o0) - 1.f;
        o1 = (o1 > 0.f) ? o1 : expf(o1) - 1.f;
        o2 = (o2 > 0.f) ? o2 : expf(o2) - 1.f;
        o3 = (o3 > 0.f) ? o3 : expf(o3) - 1.f;
    }
    float* orow = out + (size_t)i * 256;
    orow[lane] = o0;
    orow[64 + lane] = o1;
    orow[128 + lane] = o2;
    orow[192 + lane] = o3;
}

// ---------------------------------------------------------------------------
// Global max pool over the 64 sorted graph segments
// ---------------------------------------------------------------------------
__global__ __launch_bounds__(1024) void pool_max_k(const float* __restrict__ y,
                                                   float* __restrict__ g) {
    int gid = blockIdx.x;
    int t = threadIdx.x;
    int dim = t & 255;
    int s = t >> 8;  // 0..3
    int start = (gid * NN + (GG - 1)) / GG;
    int end = ((gid + 1) * NN + (GG - 1)) / GG;
    float m = -INFINITY;
    for (int i = start + s; i < end; i += 4)
        m = fmaxf(m, y[(size_t)i * 256 + dim]);
    __shared__ float red[4][256];
    red[s][dim] = m;
    __syncthreads();
    if (s == 0) {
        m = fmaxf(fmaxf(red[0][dim], red[1][dim]), fmaxf(red[2][dim], red[3][dim]));
        g[gid * 256 + dim] = m;
    }
}

// ---------------------------------------------------------------------------
// Hierarchical classifier: one block per graph
// ---------------------------------------------------------------------------
__global__ __launch_bounds__(256) void classifier_k(const float* __restrict__ g,
                                                    const float* __restrict__ Wc1, const float* __restrict__ bc1,
                                                    const float* __restrict__ Wc2, const float* __restrict__ bc2,
                                                    const float* __restrict__ Wc3, const float* __restrict__ bc3,
                                                    float* __restrict__ out) {
    __shared__ float gs[256];
    __shared__ float p1s[16];
    __shared__ float p2s[64];
    __shared__ float ls[64];
    const int gid = blockIdx.x;
    const int t = threadIdx.x;
    gs[t] = g[gid * 256 + t];
    __syncthreads();

    if (t < 16) {
        float a = bc1[t];
        for (int k = 0; k < 256; ++k) a += gs[k] * Wc1[k * 16 + t];
        out[gid * 16 + t] = a;
        ls[t] = a;
    }
    __syncthreads();
    if (t == 0) {
        float mx = -INFINITY;
        for (int j = 0; j < 16; ++j) mx = fmaxf(mx, ls[j]);
        float s = 0.f;
        for (int j = 0; j < 16; ++j) { float w = expf(ls[j] - mx); p1s[j] = w; s += w; }
        for (int j = 0; j < 16; ++j) p1s[j] /= s;
    }
    __syncthreads();

    if (t < 64) {
        float a = bc2[t];
        for (int k = 0; k < 256; ++k) a += gs[k] * Wc2[k * 64 + t];
        for (int j = 0; j < 16; ++j) a += p1s[j] * Wc2[(256 + j) * 64 + t];
        out[GG * 16 + gid * 64 + t] = a;
        ls[t] = a;
    }
    __syncthreads();
    if (t == 0) {
        float mx = -INFINITY;
        for (int j = 0; j < 64; ++j) mx = fmaxf(mx, ls[j]);
        float s = 0.f;
        for (int j = 0; j < 64; ++j) { float w = expf(ls[j] - mx); p2s[j] = w; s += w; }
        for (int j = 0; j < 64; ++j) p2s[j] /= s;
    }
    __syncthreads();

    {
        float a = bc3[t];
        for (int k = 0; k < 256; ++k) a += gs[k] * Wc3[k * 256 + t];
        for (int j = 0; j < 64; ++j) a += p2s[j] * Wc3[(256 + j) * 256 + t];
        out[GG * 16 + GG * 64 + gid * 256 + t] = a;
    }
}

// ---------------------------------------------------------------------------
// Launch
// ---------------------------------------------------------------------------
extern "C" void kernel_launch(void* const* d_in, const int* in_sizes, int n_in,
                              void* d_out, int out_size, void* d_ws, size_t ws_size,
                              hipStream_t stream) {
    const float* x   = (const float*)d_in[0];
    const int*   ei  = (const int*)d_in[1];   // [2,E] flat
    const float* W1  = (const float*)d_in[3];
    const float* as1 = (const float*)d_in[4];
    const float* ad1 = (const float*)d_in[5];
    const float* b1  = (const float*)d_in[6];
    const float* W2  = (const float*)d_in[7];
    const float* as2 = (const float*)d_in[8];
    const float* ad2 = (const float*)d_in[9];
    const float* b2  = (const float*)d_in[10];
    const float* W3  = (const float*)d_in[11];
    const float* as3 = (const float*)d_in[12];
    const float* ad3 = (const float*)d_in[13];
    const float* b3  = (const float*)d_in[14];
    const float* Wc1 = (const float*)d_in[15];
    const float* bc1 = (const float*)d_in[16];
    const float* Wc2 = (const float*)d_in[17];
    const float* bc2 = (const float*)d_in[18];
    const float* Wc3 = (const float*)d_in[19];
    const float* bc3 = (const float*)d_in[20];
    float* out = (float*)d_out;

    const int N = NN, E = EE;
    const int* e_src = ei;
    const int* e_dst = ei + E;

    // workspace carve (aligned 256B)
    char* w = (char*)d_ws;
    auto carve = [&](size_t bytes) {
        void* p = (void*)w;
        w += (bytes + 255) & ~(size_t)255;
        return p;
    };
    float* bufA   = (float*)carve((size_t)N * 256 * 4);
    float* bufB   = (float*)carve((size_t)N * 256 * 4);
    float* als    = (float*)carve((size_t)N * 4 * 4);
    float* ald    = (float*)carve((size_t)N * 4 * 4);
    int*   cnt    = (int*)carve((size_t)N * 4);
    int*   tmpv   = (int*)carve((size_t)N * 4);
    int*   bsums  = (int*)carve(1024);
    int*   row_off= (int*)carve((size_t)(N + 1) * 4);
    int*   wrp    = (int*)carve((size_t)N * 4);
    int*   csr    = (int*)carve((size_t)E * 4);
    float* gbuf   = (float*)carve((size_t)GG * 256 * 4);

    const int nScanBlocks = (N + 255) / 256;  // 196

    // ---- CSR build
    hipMemsetAsync(cnt, 0, (size_t)N * 4, stream);
    count_dst_k<<<(E + 255) / 256, 256, 0, stream>>>(e_dst, cnt, E);
    scan1_k<<<nScanBlocks, 256, 0, stream>>>(cnt, tmpv, bsums, N);
    scan2_k<<<1, 256, 0, stream>>>(bsums, nScanBlocks);
    scan3_k<<<nScanBlocks, 256, 0, stream>>>(tmpv, cnt, bsums, row_off, wrp, N);
    scatter_k<<<(E + 255) / 256, 256, 0, stream>>>(e_src, e_dst, wrp, csr, E);

    const int waveBlocks = (N * 64 + 255) / 256;  // 12500
    dim3 gemmGridK300((N + 63) / 64, 4);

    // ---- layer 1: x[N,300]@W1 -> bufA; agg -> bufB (ELU)
    gemm_f32<<<gemmGridK300, 256, 0, stream>>>(x, W1, bufA, N, INF_);
    calc_alpha_k<4><<<waveBlocks, 256, 0, stream>>>(bufA, as1, ad1, als, ald, N);
    gat_agg_k<4><<<waveBlocks, 256, 0, stream>>>(bufA, als, ald, row_off, csr, b1, bufB, N, 1);

    // ---- layer 2: bufB@W2 -> bufA; agg -> bufB (ELU)
    gemm_f32<<<gemmGridK300, 256, 0, stream>>>(bufB, W2, bufA, N, HIDF);
    calc_alpha_k<4><<<waveBlocks, 256, 0, stream>>>(bufA, as2, ad2, als, ald, N);
    gat_agg_k<4><<<waveBlocks, 256, 0, stream>>>(bufA, als, ald, row_off, csr, b2, bufB, N, 1);

    // ---- layer 3: bufB@W3 -> bufA; agg (1 head, no ELU) -> bufB
    gemm_f32<<<gemmGridK300, 256, 0, stream>>>(bufB, W3, bufA, N, HIDF);
    calc_alpha_k<1><<<waveBlocks, 256, 0, stream>>>(bufA, as3, ad3, als, ald, N);
    gat_agg_k<1><<<waveBlocks, 256, 0, stream>>>(bufA, als, ald, row_off, csr, b3, bufB, N, 0);

    // ---- pool + classifier
    pool_max_k<<<GG, 1024, 0, stream>>>(bufB, gbuf);
    classifier_k<<<GG, 256, 0, stream>>>(gbuf, Wc1, bc1, Wc2, bc2, Wc3, bc3, out);
}

// Round 7
// 1045.693 us; speedup vs baseline: 1.0507x; 1.0507x over previous
//
#include <hip/hip_runtime.h>
#include <hip/hip_bf16.h>
#include <math.h>

// Problem constants (match reference)
#define NN 50000
#define EE 800000
#define INF_ 300
#define HIDF 256
#define GG 64

// ---------------------------------------------------------------------------
// CSR build: histogram of dst, exclusive scan, scatter src ids
// ---------------------------------------------------------------------------
__global__ void count_dst_k(const int* __restrict__ dst, int* __restrict__ cnt, int E) {
    int e = blockIdx.x * blockDim.x + threadIdx.x;
    if (e < E) atomicAdd(&cnt[dst[e]], 1);
}

__global__ void scan1_k(const int* __restrict__ cnt, int* __restrict__ tmp,
                        int* __restrict__ bsums, int n) {
    __shared__ int sd[256];
    int t = threadIdx.x;
    int i = blockIdx.x * 256 + t;
    sd[t] = (i < n) ? cnt[i] : 0;
    __syncthreads();
    #pragma unroll
    for (int off = 1; off < 256; off <<= 1) {
        int add = (t >= off) ? sd[t - off] : 0;
        __syncthreads();
        sd[t] += add;
        __syncthreads();
    }
    if (i < n) tmp[i] = sd[t];
    if (t == 255) bsums[blockIdx.x] = sd[255];
}

__global__ void scan2_k(int* __restrict__ bsums, int nb) {
    __shared__ int sd[256];
    int t = threadIdx.x;
    sd[t] = (t < nb) ? bsums[t] : 0;
    __syncthreads();
    #pragma unroll
    for (int off = 1; off < 256; off <<= 1) {
        int add = (t >= off) ? sd[t - off] : 0;
        __syncthreads();
        sd[t] += add;
        __syncthreads();
    }
    if (t < nb) bsums[t] = sd[t];
}

__global__ void scan3_k(const int* __restrict__ tmp, const int* __restrict__ cnt,
                        const int* __restrict__ bsums, int* __restrict__ row_off,
                        int* __restrict__ wr, int n) {
    int i = blockIdx.x * 256 + threadIdx.x;
    if (i >= n) return;
    int base = (blockIdx.x > 0) ? bsums[blockIdx.x - 1] : 0;
    int incl = tmp[i] + base;
    row_off[i + 1] = incl;
    wr[i] = incl - cnt[i];
    if (i == 0) row_off[0] = 0;
}

__global__ void scatter_k(const int* __restrict__ src, const int* __restrict__ dst,
                          int* __restrict__ wr, int* __restrict__ csr_src, int E) {
    int e = blockIdx.x * blockDim.x + threadIdx.x;
    if (e < E) {
        int d = dst[e];
        int pos = atomicAdd(&wr[d], 1);
        csr_src[pos] = src[e];
    }
}

// ---------------------------------------------------------------------------
// fp32 GEMM v2: C[M,256] = A[M,K] @ B[K,256].
// 128x128 tile, 256 threads, 8x8 micro-tile. Skewed sB to kill 4-way bank
// conflict on the B-fragment ds_read_b128 (phys col = c + 4*(c>>5) -> 2-way).
// ---------------------------------------------------------------------------
#define SB_PHYS(c) ((c) + 4 * ((c) >> 5))

__global__ __launch_bounds__(256, 2) void gemm_f32_v2(const float* __restrict__ A,
                                                      const float* __restrict__ B,
                                                      float* __restrict__ C, int M, int K) {
    __shared__ float sA[16][128];          // [k][m]
    __shared__ float sB[16][SB_PHYS(128) + 8];  // [k][skewed n]
    const int tid = threadIdx.x;
    const int bm = blockIdx.x * 128;
    const int bn = blockIdx.y * 128;
    const int tr = tid >> 4, tc = tid & 15;
    const int r0 = tr * 8, c0 = tc * 8;
    const int c0p = SB_PHYS(c0);

    float acc[8][8] = {};

    const int aRow = tid >> 1;           // 0..127
    const int aK   = (tid & 1) * 8;      // 0 or 8
    const bool aV  = (bm + aRow) < M;
    const float* Arow = A + (size_t)(bm + aRow) * K;

    const int bRow = tid >> 4;           // 0..15
    const int bCol = (tid & 15) * 8;     // 0..120
    const int bColP = SB_PHYS(bCol);

    const int nT = (K + 15) >> 4;

    for (int t = 0; t < nT; ++t) {
        const int k0 = t * 16;
        // A tile -> sA transposed
        #pragma unroll
        for (int half = 0; half < 2; ++half) {
            const int kk = aK + half * 4;
            if (aV && (k0 + kk + 4) <= K) {
                float4 v = *(const float4*)(Arow + k0 + kk);
                sA[kk + 0][aRow] = v.x;
                sA[kk + 1][aRow] = v.y;
                sA[kk + 2][aRow] = v.z;
                sA[kk + 3][aRow] = v.w;
            } else {
                #pragma unroll
                for (int j = 0; j < 4; ++j) {
                    int k = k0 + kk + j;
                    sA[kk + j][aRow] = (aV && k < K) ? Arow[k] : 0.f;
                }
            }
        }
        // B tile (row-major, skewed columns)
        {
            const int k = k0 + bRow;
            float4 v0 = make_float4(0.f, 0.f, 0.f, 0.f), v1 = v0;
            if (k < K) {
                const float* Brow = B + (size_t)k * 256 + bn + bCol;
                v0 = *(const float4*)(Brow);
                v1 = *(const float4*)(Brow + 4);
            }
            *(float4*)&sB[bRow][bColP]     = v0;
            *(float4*)&sB[bRow][bColP + 4] = v1;
        }
        __syncthreads();
        #pragma unroll
        for (int k = 0; k < 16; ++k) {
            float4 a0 = *(float4*)&sA[k][r0];
            float4 a1 = *(float4*)&sA[k][r0 + 4];
            float4 b0 = *(float4*)&sB[k][c0p];
            float4 b1 = *(float4*)&sB[k][c0p + 4];
            float av[8] = {a0.x, a0.y, a0.z, a0.w, a1.x, a1.y, a1.z, a1.w};
            float bv[8] = {b0.x, b0.y, b0.z, b0.w, b1.x, b1.y, b1.z, b1.w};
            #pragma unroll
            for (int i = 0; i < 8; ++i)
                #pragma unroll
                for (int j = 0; j < 8; ++j)
                    acc[i][j] += av[i] * bv[j];
        }
        __syncthreads();
    }
    #pragma unroll
    for (int i = 0; i < 8; ++i) {
        const int m = bm + r0 + i;
        if (m < M) {
            float* Crow = C + (size_t)m * 256 + bn + c0;
            *(float4*)(Crow)     = make_float4(acc[i][0], acc[i][1], acc[i][2], acc[i][3]);
            *(float4*)(Crow + 4) = make_float4(acc[i][4], acc[i][5], acc[i][6], acc[i][7]);
        }
    }
}

// ---------------------------------------------------------------------------
// Per-node attention scores: als[n,h] = <h[n,h,:], a_src[h,:]>, same for ald.
// One wave per node.
// ---------------------------------------------------------------------------
template <int NH>
__global__ __launch_bounds__(256) void calc_alpha_k(const float* __restrict__ hf,
                                                    const float* __restrict__ a_s,
                                                    const float* __restrict__ a_d,
                                                    float* __restrict__ als,
                                                    float* __restrict__ ald, int n) {
    int gw = (blockIdx.x * blockDim.x + threadIdx.x) >> 6;
    int lane = threadIdx.x & 63;
    if (gw >= n) return;
    const float* hr = hf + (size_t)gw * 256;
    float ps[4], pd[4];
    #pragma unroll
    for (int j = 0; j < 4; ++j) {
        float v = hr[j * 64 + lane];
        ps[j] = v * a_s[j * 64 + lane];
        pd[j] = v * a_d[j * 64 + lane];
    }
    if (NH == 1) {
        ps[0] = (ps[0] + ps[1]) + (ps[2] + ps[3]);
        pd[0] = (pd[0] + pd[1]) + (pd[2] + pd[3]);
    }
    #pragma unroll
    for (int h = 0; h < NH; ++h) {
        float s = ps[h], d = pd[h];
        #pragma unroll
        for (int off = 32; off > 0; off >>= 1) {
            s += __shfl_xor(s, off, 64);
            d += __shfl_xor(d, off, 64);
        }
        if (lane == 0) {
            als[gw * NH + h] = s;
            ald[gw * NH + h] = d;
        }
    }
}

// ---------------------------------------------------------------------------
// GAT aggregation v2: one wave per dst node.
//   pass 1: lane-strided segment max (+self), shfl-reduce.
//   pass 2: chunks of 64 edges. Lane j computes edge j's NH weights ONCE,
//           stores to per-wave LDS; denominator accumulated lane-locally.
//           Accumulation loop: src id broadcast via v_readlane (SGPR base),
//           weight via bank-broadcast ds_read, each lane owns a contiguous
//           float4 of output dims so it needs exactly one head weight.
// ---------------------------------------------------------------------------
__device__ __forceinline__ float leaky02(float x) { return (x > 0.f) ? x : 0.2f * x; }

template <int NH>
__global__ __launch_bounds__(256) void gat_agg2_k(const float* __restrict__ hf,
                                                  const float* __restrict__ als,
                                                  const float* __restrict__ ald,
                                                  const int* __restrict__ row_off,
                                                  const int* __restrict__ csr_src,
                                                  const float* __restrict__ bias,
                                                  float* __restrict__ out, int n,
                                                  int do_elu) {
    __shared__ float wlds[4][64][NH];
    const int wslot = threadIdx.x >> 6;
    const int gw = (blockIdx.x * blockDim.x + threadIdx.x) >> 6;
    const int lane = threadIdx.x & 63;
    if (gw >= n) return;
    const int i = gw;
    const int e0 = row_off[i], e1 = row_off[i + 1];
    const int hL = (NH == 4) ? (lane >> 4) : 0;

    float adv[NH], aself[NH];
    if (NH == 4) {
        float4 v = *(const float4*)(ald + (size_t)i * 4);
        adv[0] = v.x; adv[1] = v.y; adv[2] = v.z; adv[3] = v.w;
        float4 u = *(const float4*)(als + (size_t)i * 4);
        aself[0] = u.x; aself[1] = u.y; aself[2] = u.z; aself[3] = u.w;
    } else {
        adv[0] = ald[i];
        aself[0] = als[i];
    }

    // ---- pass 1: segment max (self-loop seeds it -> always finite)
    float m[NH];
    #pragma unroll
    for (int h = 0; h < NH; ++h) m[h] = leaky02(aself[h] + adv[h]);
    for (int e = e0 + lane; e < e1; e += 64) {
        int s = csr_src[e];
        if (NH == 4) {
            float4 v = *(const float4*)(als + (size_t)s * 4);
            m[0] = fmaxf(m[0], leaky02(v.x + adv[0]));
            m[1] = fmaxf(m[1], leaky02(v.y + adv[1]));
            m[2] = fmaxf(m[2], leaky02(v.z + adv[2]));
            m[3] = fmaxf(m[3], leaky02(v.w + adv[3]));
        } else {
            m[0] = fmaxf(m[0], leaky02(als[s] + adv[0]));
        }
    }
    #pragma unroll
    for (int h = 0; h < NH; ++h)
        #pragma unroll
        for (int off = 32; off > 0; off >>= 1)
            m[h] = fmaxf(m[h], __shfl_xor(m[h], off, 64));

    // ---- self-loop contribution
    float denomL[NH];
    #pragma unroll
    for (int h = 0; h < NH; ++h) denomL[h] = 0.f;
    float wself[NH];
    #pragma unroll
    for (int h = 0; h < NH; ++h) wself[h] = expf(leaky02(aself[h] + adv[h]) - m[h]);
    if (lane == 0) {
        #pragma unroll
        for (int h = 0; h < NH; ++h) denomL[h] += wself[h];
    }
    float wsel = (NH == 4)
        ? ((lane < 16) ? wself[0] : (lane < 32) ? wself[1] : (lane < 48) ? wself[2] : wself[3])
        : wself[0];
    float4 av4 = *(const float4*)(hf + (size_t)i * 256 + 4 * lane);
    float ax = wsel * av4.x, ay = wsel * av4.y, az = wsel * av4.z, aw = wsel * av4.w;

    // ---- pass 2: chunked edges
    for (int base = e0; base < e1; base += 64) {
        const int e = base + lane;
        const bool valid = e < e1;
        int s_reg = valid ? csr_src[e] : 0;
        float w[NH];
        if (valid) {
            if (NH == 4) {
                float4 v = *(const float4*)(als + (size_t)s_reg * 4);
                w[0] = expf(leaky02(v.x + adv[0]) - m[0]);
                w[1] = expf(leaky02(v.y + adv[1]) - m[1]);
                w[2] = expf(leaky02(v.z + adv[2]) - m[2]);
                w[3] = expf(leaky02(v.w + adv[3]) - m[3]);
            } else {
                w[0] = expf(leaky02(als[s_reg] + adv[0]) - m[0]);
            }
        } else {
            #pragma unroll
            for (int h = 0; h < NH; ++h) w[h] = 0.f;
        }
        #pragma unroll
        for (int h = 0; h < NH; ++h) denomL[h] += w[h];
        if (NH == 4)
            *(float4*)&wlds[wslot][lane][0] = make_float4(w[0], w[1], w[2], w[3]);
        else
            wlds[wslot][lane][0] = w[0];

        const int cnt = min(64, e1 - base);
        #pragma unroll 4
        for (int j = 0; j < cnt; ++j) {
            int sj = __builtin_amdgcn_readlane(s_reg, j);       // SGPR broadcast
            float wj = wlds[wslot][j][hL];                      // bank-broadcast
            const float4 hv = *(const float4*)(hf + (size_t)sj * 256 + 4 * lane);
            ax += wj * hv.x; ay += wj * hv.y; az += wj * hv.z; aw += wj * hv.w;
        }
    }

    // ---- denominator reduce + epilogue
    #pragma unroll
    for (int h = 0; h < NH; ++h)
        #pragma unroll
        for (int off = 32; off > 0; off >>= 1)
            denomL[h] += __shfl_xor(denomL[h], off, 64);
    float dh = (NH == 4)
        ? ((lane < 16) ? denomL[0] : (lane < 32) ? denomL[1] : (lane < 48) ? denomL[2] : denomL[3])
        : denomL[0];
    float inv = 1.f / (dh + 1e-16f);
    float4 bv = *(const float4*)(bias + 4 * lane);
    float o0 = ax * inv + bv.x;
    float o1 = ay * inv + bv.y;
    float o2 = az * inv + bv.z;
    float o3 = aw * inv + bv.w;
    if (do_elu) {
        o0 = (o0 > 0.f) ? o0 : expf(o0) - 1.f;
        o1 = (o1 > 0.f) ? o1 : expf(o1) - 1.f;
        o2 = (o2 > 0.f) ? o2 : expf(o2) - 1.f;
        o3 = (o3 > 0.f) ? o3 : expf(o3) - 1.f;
    }
    *(float4*)(out + (size_t)i * 256 + 4 * lane) = make_float4(o0, o1, o2, o3);
}

// ---------------------------------------------------------------------------
// Global max pool over the 64 sorted graph segments
// ---------------------------------------------------------------------------
__global__ __launch_bounds__(1024) void pool_max_k(const float* __restrict__ y,
                                                   float* __restrict__ g) {
    int gid = blockIdx.x;
    int t = threadIdx.x;
    int dim = t & 255;
    int s = t >> 8;  // 0..3
    int start = (gid * NN + (GG - 1)) / GG;
    int end = ((gid + 1) * NN + (GG - 1)) / GG;
    float m = -INFINITY;
    for (int i = start + s; i < end; i += 4)
        m = fmaxf(m, y[(size_t)i * 256 + dim]);
    __shared__ float red[4][256];
    red[s][dim] = m;
    __syncthreads();
    if (s == 0) {
        m = fmaxf(fmaxf(red[0][dim], red[1][dim]), fmaxf(red[2][dim], red[3][dim]));
        g[gid * 256 + dim] = m;
    }
}

// ---------------------------------------------------------------------------
// Hierarchical classifier: one block per graph
// ---------------------------------------------------------------------------
__global__ __launch_bounds__(256) void classifier_k(const float* __restrict__ g,
                                                    const float* __restrict__ Wc1, const float* __restrict__ bc1,
                                                    const float* __restrict__ Wc2, const float* __restrict__ bc2,
                                                    const float* __restrict__ Wc3, const float* __restrict__ bc3,
                                                    float* __restrict__ out) {
    __shared__ float gs[256];
    __shared__ float p1s[16];
    __shared__ float p2s[64];
    __shared__ float ls[64];
    const int gid = blockIdx.x;
    const int t = threadIdx.x;
    gs[t] = g[gid * 256 + t];
    __syncthreads();

    if (t < 16) {
        float a = bc1[t];
        for (int k = 0; k < 256; ++k) a += gs[k] * Wc1[k * 16 + t];
        out[gid * 16 + t] = a;
        ls[t] = a;
    }
    __syncthreads();
    if (t == 0) {
        float mx = -INFINITY;
        for (int j = 0; j < 16; ++j) mx = fmaxf(mx, ls[j]);
        float s = 0.f;
        for (int j = 0; j < 16; ++j) { float w = expf(ls[j] - mx); p1s[j] = w; s += w; }
        for (int j = 0; j < 16; ++j) p1s[j] /= s;
    }
    __syncthreads();

    if (t < 64) {
        float a = bc2[t];
        for (int k = 0; k < 256; ++k) a += gs[k] * Wc2[k * 64 + t];
        for (int j = 0; j < 16; ++j) a += p1s[j] * Wc2[(256 + j) * 64 + t];
        out[GG * 16 + gid * 64 + t] = a;
        ls[t] = a;
    }
    __syncthreads();
    if (t == 0) {
        float mx = -INFINITY;
        for (int j = 0; j < 64; ++j) mx = fmaxf(mx, ls[j]);
        float s = 0.f;
        for (int j = 0; j < 64; ++j) { float w = expf(ls[j] - mx); p2s[j] = w; s += w; }
        for (int j = 0; j < 64; ++j) p2s[j] /= s;
    }
    __syncthreads();

    {
        float a = bc3[t];
        for (int k = 0; k < 256; ++k) a += gs[k] * Wc3[k * 256 + t];
        for (int j = 0; j < 64; ++j) a += p2s[j] * Wc3[(256 + j) * 256 + t];
        out[GG * 16 + GG * 64 + gid * 256 + t] = a;
    }
}

// ---------------------------------------------------------------------------
// Launch
// ---------------------------------------------------------------------------
extern "C" void kernel_launch(void* const* d_in, const int* in_sizes, int n_in,
                              void* d_out, int out_size, void* d_ws, size_t ws_size,
                              hipStream_t stream) {
    const float* x   = (const float*)d_in[0];
    const int*   ei  = (const int*)d_in[1];   // [2,E] flat
    const float* W1  = (const float*)d_in[3];
    const float* as1 = (const float*)d_in[4];
    const float* ad1 = (const float*)d_in[5];
    const float* b1  = (const float*)d_in[6];
    const float* W2  = (const float*)d_in[7];
    const float* as2 = (const float*)d_in[8];
    const float* ad2 = (const float*)d_in[9];
    const float* b2  = (const float*)d_in[10];
    const float* W3  = (const float*)d_in[11];
    const float* as3 = (const float*)d_in[12];
    const float* ad3 = (const float*)d_in[13];
    const float* b3  = (const float*)d_in[14];
    const float* Wc1 = (const float*)d_in[15];
    const float* bc1 = (const float*)d_in[16];
    const float* Wc2 = (const float*)d_in[17];
    const float* bc2 = (const float*)d_in[18];
    const float* Wc3 = (const float*)d_in[19];
    const float* bc3 = (const float*)d_in[20];
    float* out = (float*)d_out;

    const int N = NN, E = EE;
    const int* e_src = ei;
    const int* e_dst = ei + E;

    // workspace carve (aligned 256B)
    char* w = (char*)d_ws;
    auto carve = [&](size_t bytes) {
        void* p = (void*)w;
        w += (bytes + 255) & ~(size_t)255;
        return p;
    };
    float* bufA   = (float*)carve((size_t)N * 256 * 4);
    float* bufB   = (float*)carve((size_t)N * 256 * 4);
    float* als    = (float*)carve((size_t)N * 4 * 4);
    float* ald    = (float*)carve((size_t)N * 4 * 4);
    int*   cnt    = (int*)carve((size_t)N * 4);
    int*   tmpv   = (int*)carve((size_t)N * 4);
    int*   bsums  = (int*)carve(1024);
    int*   row_off= (int*)carve((size_t)(N + 1) * 4);
    int*   wrp    = (int*)carve((size_t)N * 4);
    int*   csr    = (int*)carve((size_t)E * 4);
    float* gbuf   = (float*)carve((size_t)GG * 256 * 4);

    const int nScanBlocks = (N + 255) / 256;  // 196

    // ---- CSR build
    hipMemsetAsync(cnt, 0, (size_t)N * 4, stream);
    count_dst_k<<<(E + 255) / 256, 256, 0, stream>>>(e_dst, cnt, E);
    scan1_k<<<nScanBlocks, 256, 0, stream>>>(cnt, tmpv, bsums, N);
    scan2_k<<<1, 256, 0, stream>>>(bsums, nScanBlocks);
    scan3_k<<<nScanBlocks, 256, 0, stream>>>(tmpv, cnt, bsums, row_off, wrp, N);
    scatter_k<<<(E + 255) / 256, 256, 0, stream>>>(e_src, e_dst, wrp, csr, E);

    const int waveBlocks = (N * 64 + 255) / 256;  // 12500
    dim3 gemmGrid((N + 127) / 128, 2);

    // ---- layer 1: x[N,300]@W1 -> bufA; agg -> bufB (ELU)
    gemm_f32_v2<<<gemmGrid, 256, 0, stream>>>(x, W1, bufA, N, INF_);
    calc_alpha_k<4><<<waveBlocks, 256, 0, stream>>>(bufA, as1, ad1, als, ald, N);
    gat_agg2_k<4><<<waveBlocks, 256, 0, stream>>>(bufA, als, ald, row_off, csr, b1, bufB, N, 1);

    // ---- layer 2: bufB@W2 -> bufA; agg -> bufB (ELU)
    gemm_f32_v2<<<gemmGrid, 256, 0, stream>>>(bufB, W2, bufA, N, HIDF);
    calc_alpha_k<4><<<waveBlocks, 256, 0, stream>>>(bufA, as2, ad2, als, ald, N);
    gat_agg2_k<4><<<waveBlocks, 256, 0, stream>>>(bufA, als, ald, row_off, csr, b2, bufB, N, 1);

    // ---- layer 3: bufB@W3 -> bufA; agg (1 head, no ELU) -> bufB
    gemm_f32_v2<<<gemmGrid, 256, 0, stream>>>(bufB, W3, bufA, N, HIDF);
    calc_alpha_k<1><<<waveBlocks, 256, 0, stream>>>(bufA, as3, ad3, als, ald, N);
    gat_agg2_k<1><<<waveBlocks, 256, 0, stream>>>(bufA, als, ald, row_off, csr, b3, bufB, N, 0);

    // ---- pool + classifier
    pool_max_k<<<GG, 1024, 0, stream>>>(bufB, gbuf);
    classifier_k<<<GG, 256, 0, stream>>>(gbuf, Wc1, bc1, Wc2, bc2, Wc3, bc3, out);
}